// Round 5
// baseline (314.128 us; speedup 1.0000x reference)
//
#include <hip/hip_runtime.h>
#include <hip/hip_cooperative_groups.h>

namespace cg = cooperative_groups;

// ExpertMLP, single cooperative kernel (512 blocks x 256 thr, 4 grid.sync):
//  P0 prep: x->bf16; w1,w2 -> bf16 [e][n][k] transposes
//  P1 gemm1: P[e] = xb @ W1[e]   (128x64 tiles, swizzled LDS, R2/R4-proven)
//  P2 blend1: h = sum_e coef*(P+b1); BN col-stat partials (shuffle tree, no atomics)
//  P3 gemm2: P[e] = elu(BN(h)) @ W2[e]  (BN+ELU fused into A-staging)
//  P4 blend2: out = sum_e coef*(P+b2)

typedef short bf16x8 __attribute__((ext_vector_type(8)));
typedef float f32x4 __attribute__((ext_vector_type(4)));
typedef unsigned short u16;
typedef u16 u16x4 __attribute__((ext_vector_type(4)));
typedef u16 u16x8 __attribute__((ext_vector_type(8)));

__device__ __forceinline__ u16 f2bf(float f) {
  union { float f; unsigned u; } v; v.f = f;
  return (u16)((v.u + 0x7FFFu + ((v.u >> 16) & 1u)) >> 16);  // RNE
}

#define AS_G(p) ((const __attribute__((address_space(1))) void*)(p))
#define AS_L(p) ((__attribute__((address_space(3))) void*)(p))

// ---------------- P0: x convert + weight transposes (bid in [0,512)) --------
__device__ __forceinline__ void prep_phase(int bid, int t, char* smem,
    const float* __restrict__ x, const float* __restrict__ w1,
    const float* __restrict__ w2, u16* __restrict__ xb,
    u16* __restrict__ w1t, u16* __restrict__ w2t)
{
  float (*ld)[65] = (float (*)[65])smem;     // 64x65 f32, padded
  {                                          // x -> bf16 (all 512 blocks)
    int idx = bid * 256 + t;
    f32x4 v = *(const f32x4*)(x + (size_t)idx * 4);
    u16x4 o; o.x = f2bf(v.x); o.y = f2bf(v.y); o.z = f2bf(v.z); o.w = f2bf(v.w);
    *(u16x4*)(xb + (size_t)idx * 4) = o;
  }
  #pragma unroll
  for (int rep = 0; rep < 2; ++rep) {        // 1024 transpose tiles, 2 per block
    int job = bid + rep * 512;
    const float* src = (job >> 9) ? w2 : w1;
    u16* dst = (job >> 9) ? w2t : w1t;
    int rem = job & 511, e = rem >> 6, tl = rem & 63;
    int kt = tl >> 3, nt = tl & 7;
    __syncthreads();
    #pragma unroll
    for (int j = 0; j < 4; ++j) {            // read [k][n] coalesced
      int kr = j * 16 + (t >> 4), nc = (t & 15) * 4;
      f32x4 v = *(const f32x4*)(src + (size_t)(e * 512 + kt * 64 + kr) * 512 + nt * 64 + nc);
      ld[kr][nc] = v.x; ld[kr][nc + 1] = v.y; ld[kr][nc + 2] = v.z; ld[kr][nc + 3] = v.w;
    }
    __syncthreads();
    #pragma unroll
    for (int j = 0; j < 4; ++j) {            // write [n][k] coalesced, bf16
      int nr = j * 16 + (t >> 4), kc = (t & 15) * 4;
      u16x4 o;
      o.x = f2bf(ld[kc][nr]);     o.y = f2bf(ld[kc + 1][nr]);
      o.z = f2bf(ld[kc + 2][nr]); o.w = f2bf(ld[kc + 3][nr]);
      *(u16x4*)(dst + (size_t)(e * 512 + nt * 64 + nr) * 512 + kt * 64 + kc) = o;
    }
  }
}

// ---------------- gemm: P[e] = A @ W[e], 128x64 tile, BK=64, swizzled LDS ----
// swizzle: phys chunk = logical ^ (row&7); global_load_lds source pre-swizzled.
template <int LAYER>
__device__ __forceinline__ void gemm_phase(int bid, int t, char* smem,
    const u16* __restrict__ Axb, const float* __restrict__ H,
    const u16* __restrict__ Wt,
    const float* __restrict__ sP, const float* __restrict__ qP,
    const float* __restrict__ gamma, const float* __restrict__ beta,
    float* __restrict__ P)
{
  u16* As = (u16*)smem;                      // [128][64] swizzled, 16 KB
  u16* Bs = (u16*)(smem + 16384);            // [64][64]  swizzled,  8 KB
  float* scale_s = (float*)(smem + 24576);   // 2 KB
  float* shift_s = (float*)(smem + 26624);   // 2 KB

  int e = bid & 7;                           // expert == XCD round-robin
  int tile = bid >> 3, mt = tile >> 3, nt = tile & 7;
  int l = t & 63, w = t >> 6, wm = w >> 1, wn = w & 1;   // wave tile 64x32

  if constexpr (LAYER == 2) {                // reduce 16 stat partials -> BN params
    for (int c = t; c < 512; c += 256) {
      float S = 0.f, Q = 0.f;
      #pragma unroll
      for (int p = 0; p < 16; ++p) { S += sP[p * 512 + c]; Q += qP[p * 512 + c]; }
      float mean = S * (1.0f / 1024.0f);
      float var  = Q * (1.0f / 1024.0f) - mean * mean;   // biased, matches ref
      float sc = gamma[c] * rsqrtf(var + 1e-5f);
      scale_s[c] = sc; shift_s[c] = beta[c] - mean * sc;
    }
    __syncthreads();
  }

  f32x4 acc[4][2] = {};
  const u16* Bg = Wt + (size_t)(e * 512 + nt * 64) * 512;
  int lr = l >> 3, swz = ((l & 7) ^ lr) * 8;

  for (int kt = 0; kt < 8; ++kt) {
    int k0 = kt * 64;
    #pragma unroll
    for (int j = 0; j < 2; ++j) {            // stage B 64x64
      int rb = w * 16 + j * 8;
      __builtin_amdgcn_global_load_lds(AS_G(Bg + (size_t)(rb + lr) * 512 + k0 + swz),
                                       AS_L(&Bs[rb * 64]), 16, 0, 0);
    }
    if constexpr (LAYER == 1) {              // stage A 128x64 from xb
      #pragma unroll
      for (int j = 0; j < 4; ++j) {
        int row = j * 32 + w * 8;
        __builtin_amdgcn_global_load_lds(AS_G(Axb + (size_t)(mt * 128 + row + lr) * 512 + k0 + swz),
                                         AS_L(&As[row * 64]), 16, 0, 0);
      }
    } else {                                 // reg-stage h + BN + ELU + cast
      #pragma unroll
      for (int pj = 0; pj < 4; ++pj) {
        int p = pj * 256 + t;                // phys chunk 0..1023
        int row = p >> 3, cl = (p & 7) ^ (row & 7);
        const float* hsrc = H + (size_t)(mt * 128 + row) * 512 + k0 + cl * 8;
        f32x4 v0 = *(const f32x4*)hsrc;
        f32x4 v1 = *(const f32x4*)(hsrc + 4);
        f32x4 s0 = *(const f32x4*)(scale_s + k0 + cl * 8);
        f32x4 s1 = *(const f32x4*)(scale_s + k0 + cl * 8 + 4);
        f32x4 f0 = *(const f32x4*)(shift_s + k0 + cl * 8);
        f32x4 f1 = *(const f32x4*)(shift_s + k0 + cl * 8 + 4);
        u16x8 o;
        #pragma unroll
        for (int i = 0; i < 4; ++i) { float hn = v0[i] * s0[i] + f0[i]; o[i]     = f2bf(hn > 0.f ? hn : expm1f(hn)); }
        #pragma unroll
        for (int i = 0; i < 4; ++i) { float hn = v1[i] * s1[i] + f1[i]; o[4 + i] = f2bf(hn > 0.f ? hn : expm1f(hn)); }
        *(u16x8*)&As[p * 8] = o;             // linear b128 write: conflict-free
      }
    }
    __syncthreads();
    #pragma unroll
    for (int kk = 0; kk < 2; ++kk) {
      int c = kk * 4 + (l >> 4);             // logical chunk for fragment
      bf16x8 af[4], bb[2];
      #pragma unroll
      for (int m = 0; m < 4; ++m) {
        int row = wm * 64 + m * 16 + (l & 15);
        af[m] = *(const bf16x8*)&As[row * 64 + ((c ^ (row & 7)) << 3)];
      }
      #pragma unroll
      for (int n = 0; n < 2; ++n) {
        int row = wn * 32 + n * 16 + (l & 15);
        bb[n] = *(const bf16x8*)&Bs[row * 64 + ((c ^ (row & 7)) << 3)];
      }
      #pragma unroll
      for (int m = 0; m < 4; ++m)
        #pragma unroll
        for (int n = 0; n < 2; ++n)
          acc[m][n] = __builtin_amdgcn_mfma_f32_16x16x32_bf16(af[m], bb[n], acc[m][n], 0, 0, 0);
    }
    __syncthreads();
  }
  // epilogue: C/D layout col=lane&15, row=(lane>>4)*4+reg (HW-verified)
  float* Pe = P + (size_t)((e << 10) + mt * 128 + wm * 64) * 512 + nt * 64 + wn * 32;
  #pragma unroll
  for (int m = 0; m < 4; ++m)
    #pragma unroll
    for (int n = 0; n < 2; ++n) {
      int col = n * 16 + (l & 15);
      int rbase = m * 16 + (l >> 4) * 4;
      #pragma unroll
      for (int r = 0; r < 4; ++r)
        Pe[(size_t)(rbase + r) * 512 + col] = acc[m][n][r];
    }
}

// ---------------- blend: out = sum_e coef*(P[e]+bias); STATS: col partials ---
template <int STATS>
__device__ __forceinline__ void blend_phase(int bid, int t, char* smem,
    const float* __restrict__ P, const float* __restrict__ coef,
    const float* __restrict__ bias, float* __restrict__ o,
    float* __restrict__ sP, float* __restrict__ qP)
{
  f32x4* redS = (f32x4*)smem;                // [4][4]
  f32x4* redQ = redS + 16;
  int mblk = bid >> 5, cblk = bid & 31;      // 16 row-blocks x 32 col-blocks
  int w = t >> 6, l = t & 63;
  int row = mblk * 64 + (t >> 2);
  int col = cblk * 16 + (t & 3) * 4;
  const float* cr = coef + row * 8;
  f32x4 acc = {0, 0, 0, 0};
  #pragma unroll
  for (int e = 0; e < 8; ++e) {
    float c = cr[e];
    f32x4 p = *(const f32x4*)(P + (size_t)((e << 10) + row) * 512 + col);
    f32x4 bb = *(const f32x4*)(bias + e * 512 + col);
    acc += c * (p + bb);
  }
  *(f32x4*)(o + (size_t)row * 512 + col) = acc;
  if constexpr (STATS) {
    f32x4 sq = acc * acc;
    #pragma unroll
    for (int off = 4; off < 64; off <<= 1) { // butterfly over the 16 rows/wave
      #pragma unroll
      for (int i = 0; i < 4; ++i) {
        acc[i] += __shfl_xor(acc[i], off);
        sq[i]  += __shfl_xor(sq[i],  off);
      }
    }
    if (l < 4) { redS[w * 4 + l] = acc; redQ[w * 4 + l] = sq; }
    __syncthreads();
    if (w == 0 && l < 4) {                   // fixed-order wave combine: deterministic
      f32x4 S = redS[l] + redS[4 + l] + redS[8 + l] + redS[12 + l];
      f32x4 Q = redQ[l] + redQ[4 + l] + redQ[8 + l] + redQ[12 + l];
      #pragma unroll
      for (int i = 0; i < 4; ++i) {
        sP[mblk * 512 + cblk * 16 + l * 4 + i] = S[i];
        qP[mblk * 512 + cblk * 16 + l * 4 + i] = Q[i];
      }
    }
  }
}

// ---------------- single cooperative kernel ---------------------------------
__global__ __launch_bounds__(256) void fused_all(
    const float* x, const float* coef, const float* w1, const float* b1,
    const float* w2, const float* b2, const float* gamma, const float* beta,
    float* out, u16* xb, u16* w1t, u16* w2t, float* h, float* prt,
    float* sP, float* qP)
{
  __shared__ __align__(16) char smem[28672];
  int bid = blockIdx.x, t = threadIdx.x;
  cg::grid_group grid = cg::this_grid();
  prep_phase(bid, t, smem, x, w1, w2, xb, w1t, w2t);
  grid.sync();
  gemm_phase<1>(bid, t, smem, xb, nullptr, w1t, nullptr, nullptr, nullptr, nullptr, prt);
  grid.sync();
  blend_phase<1>(bid, t, smem, prt, coef, b1, h, sP, qP);
  grid.sync();
  gemm_phase<2>(bid, t, smem, nullptr, h, w2t, sP, qP, gamma, beta, prt);
  grid.sync();
  blend_phase<0>(bid, t, smem, prt, coef, b2, out, nullptr, nullptr);
}

// ---------------- non-cooperative fallback wrappers --------------------------
__global__ __launch_bounds__(256) void prep_g(
    const float* x, const float* w1, const float* w2,
    u16* xb, u16* w1t, u16* w2t)
{
  __shared__ __align__(16) char smem[28672];
  prep_phase(blockIdx.x, threadIdx.x, smem, x, w1, w2, xb, w1t, w2t);
}
template <int LAYER>
__global__ __launch_bounds__(256) void gemm_g(
    const u16* Axb, const float* H, const u16* Wt,
    const float* sP, const float* qP, const float* gamma, const float* beta,
    float* P)
{
  __shared__ __align__(16) char smem[28672];
  gemm_phase<LAYER>(blockIdx.x, threadIdx.x, smem, Axb, H, Wt, sP, qP, gamma, beta, P);
}
template <int STATS>
__global__ __launch_bounds__(256) void blend_g(
    const float* P, const float* coef, const float* bias, float* o,
    float* sP, float* qP)
{
  __shared__ __align__(16) char smem[28672];
  blend_phase<STATS>(blockIdx.x, threadIdx.x, smem, P, coef, bias, o, sP, qP);
}

extern "C" void kernel_launch(void* const* d_in, const int* in_sizes, int n_in,
                              void* d_out, int out_size, void* d_ws, size_t ws_size,
                              hipStream_t stream)
{
  const float* x     = (const float*)d_in[0];
  const float* coef  = (const float*)d_in[1];
  const float* w1    = (const float*)d_in[2];
  const float* b1    = (const float*)d_in[3];
  const float* w2    = (const float*)d_in[4];
  const float* b2    = (const float*)d_in[5];
  const float* gamma = (const float*)d_in[6];
  const float* beta  = (const float*)d_in[7];
  float* out = (float*)d_out;

  char* ws = (char*)d_ws;
  u16* w1t  = (u16*)(ws);                          //  4 MB [8][512n][512k] bf16
  u16* w2t  = (u16*)(ws + (4u << 20));             //  4 MB
  u16* xb   = (u16*)(ws + (8u << 20));             //  1 MB [1024][512] bf16
  float* h  = (float*)(ws + (9u << 20));           //  2 MB [1024][512] f32
  float* prt= (float*)(ws + (11u << 20));          // 16 MB [8][1024][512] f32
  float* sP = (float*)(ws + (27u << 20));          // 32 KB [16][512] col sums
  float* qP = (float*)(ws + (27u << 20) + 65536);  // 32 KB [16][512] col sumsq

  void* args[] = {&x, &coef, &w1, &b1, &w2, &b2, &gamma, &beta,
                  &out, &xb, &w1t, &w2t, &h, &prt, &sP, &qP};
  hipError_t err = hipLaunchCooperativeKernel((void*)fused_all, dim3(512), dim3(256),
                                              args, 0, stream);
  if (err != hipSuccess) {                   // fallback: same math, 5 nodes
    prep_g<<<512, 256, 0, stream>>>(x, w1, w2, xb, w1t, w2t);
    gemm_g<1><<<512, 256, 0, stream>>>(xb, nullptr, w1t, nullptr, nullptr, nullptr, nullptr, prt);
    blend_g<1><<<512, 256, 0, stream>>>(prt, coef, b1, h, sP, qP);
    gemm_g<2><<<512, 256, 0, stream>>>(nullptr, h, w2t, sP, qP, gamma, beta, prt);
    blend_g<0><<<512, 256, 0, stream>>>(prt, coef, b2, out, nullptr, nullptr);
  }
}

// Round 6
// 66.870 us; speedup vs baseline: 4.6976x; 4.6976x over previous
//
#include <hip/hip_runtime.h>

// ExpertMLP R6: 4 nodes, LDS-free direct-fragment GEMMs (problem is L2-resident;
// staging through LDS doubles byte movement for nothing).
//  prep:  x->bf16; w1,w2 -> bf16 [e*512+n][512k] transposes
//  gemm1: 256 blocks, 8 waves = 8 experts, 32x64 tile, K=512/wave, frags from L2;
//         coef-scaled in-reg, fixed-order LDS tree blend, bias, stat partials
//  bnelu: reduce partials -> BN scale/shift; elu transform h -> h1b (bf16), once
//  gemm2: same as gemm1 reading h1b, writes out

typedef short bf16x8 __attribute__((ext_vector_type(8)));
typedef float f32x4 __attribute__((ext_vector_type(4)));
typedef unsigned short u16;
typedef u16 u16x4 __attribute__((ext_vector_type(4)));
typedef u16 u16x8 __attribute__((ext_vector_type(8)));

__device__ __forceinline__ u16 f2bf(float f) {
  union { float f; unsigned u; } v; v.f = f;
  return (u16)((v.u + 0x7FFFu + ((v.u >> 16) & 1u)) >> 16);  // RNE
}

// ---------------- prep: x->bf16; w1,w2 -> bf16 [e][n][k] (R4-proven) --------
__global__ __launch_bounds__(256) void prep_kernel(
    const float* __restrict__ x, const float* __restrict__ w1,
    const float* __restrict__ w2, u16* __restrict__ xb,
    u16* __restrict__ w1t, u16* __restrict__ w2t)
{
  int bid = blockIdx.x, t = threadIdx.x;
  __shared__ float ld[64][65];   // +1 pad breaks col-read conflicts
  if (bid < 128) {               // convert x
    int p = (bid * 256 + t) * 16;
    #pragma unroll
    for (int i = 0; i < 4; ++i) {
      f32x4 v = *(const f32x4*)(x + p + i * 4);
      u16x4 o;
      o.x = f2bf(v.x); o.y = f2bf(v.y); o.z = f2bf(v.z); o.w = f2bf(v.w);
      *(u16x4*)(xb + p + i * 4) = o;
    }
    return;
  }
  int b2 = bid - 128;                        // 1024 blocks: 2 weights * 8 e * 64 tiles
  const float* src = (b2 >> 9) ? w2 : w1;
  u16* dst = (b2 >> 9) ? w2t : w1t;
  int rem = b2 & 511;
  int e = rem >> 6, tl = rem & 63;
  int kt = tl >> 3, nt = tl & 7;             // 64x64 tile at (kt,nt)
  #pragma unroll
  for (int j = 0; j < 4; ++j) {              // read [k][n] coalesced
    int kr = j * 16 + (t >> 4), nc = (t & 15) * 4;
    f32x4 v = *(const f32x4*)(src + (size_t)((e * 512 + kt * 64 + kr)) * 512 + nt * 64 + nc);
    ld[kr][nc] = v.x; ld[kr][nc + 1] = v.y; ld[kr][nc + 2] = v.z; ld[kr][nc + 3] = v.w;
  }
  __syncthreads();
  #pragma unroll
  for (int j = 0; j < 4; ++j) {              // write [n][k] coalesced, bf16
    int nr = j * 16 + (t >> 4), kc = (t & 15) * 4;
    u16x4 o;
    o.x = f2bf(ld[kc][nr]);     o.y = f2bf(ld[kc + 1][nr]);
    o.z = f2bf(ld[kc + 2][nr]); o.w = f2bf(ld[kc + 3][nr]);
    *(u16x4*)(dst + (size_t)((e * 512 + nt * 64 + nr)) * 512 + kt * 64 + kc) = o;
  }
}

// ---------------- direct-fragment blended GEMM ------------------------------
// 256 blocks (mt 0..31 x nt 0..7), 512 thr = 8 waves, wave = expert e.
// Wave computes full 32x64 tile for its expert (K=512, 16 steps x 8 MFMA),
// fragments read directly from L2 (no LDS staging). Fixed-order tree reduce.
template <int LAYER>
__global__ __launch_bounds__(512, 2) void gemm_direct(
    const u16* __restrict__ A,        // xb or h1b [1024][512] bf16
    const u16* __restrict__ Wt,       // [e*512+n][512] bf16
    const float* __restrict__ coef,   // [1024][8]
    const float* __restrict__ bias,   // [8][512]
    float* __restrict__ Out,          // h (f32) or out
    float* __restrict__ sP, float* __restrict__ qP)   // [32][512] partials
{
  int raw = blockIdx.x;                      // nt = raw&7 -> same-nt tiles share
  int nt = raw & 7, mt = raw >> 3;           //   one XCD's L2 (B-panel hot)
  int t = threadIdx.x, l = t & 63, e = t >> 6;
  __shared__ float red[4][32 * 68];          // 4 reduce slots, padded rows

  const u16* Ab = A + (size_t)(mt * 32 + (l & 15)) * 512 + ((l >> 4) * 8);
  const u16* Bb = Wt + (size_t)(e * 512 + nt * 64 + (l & 15)) * 512 + ((l >> 4) * 8);

  f32x4 acc[2][4] = {};
  bf16x8 bfr[2][4];
  #pragma unroll
  for (int n = 0; n < 4; ++n)                // preload B step 0
    bfr[0][n] = *(const bf16x8*)(Bb + (size_t)n * 16 * 512);

  #pragma unroll
  for (int s = 0; s < 16; ++s) {             // fully unrolled: static dbuf idx
    const int cur = s & 1, nxt = cur ^ 1;
    if (s < 15) {
      #pragma unroll
      for (int n = 0; n < 4; ++n)            // prefetch next B (L2)
        bfr[nxt][n] = *(const bf16x8*)(Bb + (size_t)n * 16 * 512 + (s + 1) * 32);
    }
    bf16x8 af[2];
    #pragma unroll
    for (int m = 0; m < 2; ++m)              // A-panel is L1-resident (32KB, shared)
      af[m] = *(const bf16x8*)(Ab + (size_t)m * 16 * 512 + s * 32);
    #pragma unroll
    for (int m = 0; m < 2; ++m)
      #pragma unroll
      for (int n = 0; n < 4; ++n)
        acc[m][n] = __builtin_amdgcn_mfma_f32_16x16x32_bf16(af[m], bfr[cur][n], acc[m][n], 0, 0, 0);
  }

  // scale by coef[row, e] (C/D layout: row=(l>>4)*4+r+16m, col=n*16+(l&15))
  int rl = (l >> 4) * 4;
  #pragma unroll
  for (int m = 0; m < 2; ++m) {
    #pragma unroll
    for (int r = 0; r < 4; ++r) {
      float cf = coef[(size_t)(mt * 32 + m * 16 + rl + r) * 8 + e];
      #pragma unroll
      for (int n = 0; n < 4; ++n) acc[m][n][r] *= cf;
    }
  }

  // fixed-order tree reduce across the 8 expert-waves (deterministic)
#define RED_STORE(slot)                                                       \
  { _Pragma("unroll") for (int m = 0; m < 2; ++m)                             \
    _Pragma("unroll") for (int n = 0; n < 4; ++n)                             \
    _Pragma("unroll") for (int r = 0; r < 4; ++r)                             \
      red[slot][(m * 16 + rl + r) * 68 + n * 16 + (l & 15)] = acc[m][n][r]; }
#define RED_ADD(slot)                                                         \
  { _Pragma("unroll") for (int m = 0; m < 2; ++m)                             \
    _Pragma("unroll") for (int n = 0; n < 4; ++n)                             \
    _Pragma("unroll") for (int r = 0; r < 4; ++r)                             \
      acc[m][n][r] += red[slot][(m * 16 + rl + r) * 68 + n * 16 + (l & 15)]; }

  if (e >= 4) RED_STORE(e - 4);
  __syncthreads();
  if (e < 4) RED_ADD(e);
  __syncthreads();
  if (e == 2 || e == 3) RED_STORE(e - 2);
  __syncthreads();
  if (e < 2) RED_ADD(e);
  __syncthreads();
  if (e == 1) RED_STORE(0);
  __syncthreads();

  if (e == 0) {                              // wave 0: bias blend + write + stats
    RED_ADD(0);
    int col0 = nt * 64;
    float bcol[4][8];                        // bias[e2][col(n)] hoisted
    #pragma unroll
    for (int n = 0; n < 4; ++n)
      #pragma unroll
      for (int e2 = 0; e2 < 8; ++e2)
        bcol[n][e2] = bias[e2 * 512 + col0 + n * 16 + (l & 15)];
    float sS[4] = {0.f, 0.f, 0.f, 0.f}, sQ[4] = {0.f, 0.f, 0.f, 0.f};
    #pragma unroll
    for (int m = 0; m < 2; ++m)
      #pragma unroll
      for (int r = 0; r < 4; ++r) {
        int rowg = mt * 32 + m * 16 + rl + r;
        f32x4 c0 = *(const f32x4*)(coef + (size_t)rowg * 8);
        f32x4 c1 = *(const f32x4*)(coef + (size_t)rowg * 8 + 4);
        #pragma unroll
        for (int n = 0; n < 4; ++n) {
          float bb = c0[0]*bcol[n][0] + c0[1]*bcol[n][1] + c0[2]*bcol[n][2] + c0[3]*bcol[n][3]
                   + c1[0]*bcol[n][4] + c1[1]*bcol[n][5] + c1[2]*bcol[n][6] + c1[3]*bcol[n][7];
          float v = acc[m][n][r] + bb;
          Out[(size_t)rowg * 512 + col0 + n * 16 + (l & 15)] = v;
          if constexpr (LAYER == 1) { sS[n] += v; sQ[n] += v * v; }
        }
      }
    if constexpr (LAYER == 1) {              // col sums over 32 rows -> slot [mt]
      #pragma unroll
      for (int n = 0; n < 4; ++n) {
        sS[n] += __shfl_xor(sS[n], 16); sS[n] += __shfl_xor(sS[n], 32);
        sQ[n] += __shfl_xor(sQ[n], 16); sQ[n] += __shfl_xor(sQ[n], 32);
      }
      if (l < 16) {
        #pragma unroll
        for (int n = 0; n < 4; ++n) {
          sP[mt * 512 + col0 + n * 16 + l] = sS[n];
          qP[mt * 512 + col0 + n * 16 + l] = sQ[n];
        }
      }
    }
  }
#undef RED_STORE
#undef RED_ADD
}

// ---------------- bnelu: reduce partials; h -> elu(BN(h)) bf16, once --------
__global__ __launch_bounds__(256) void bnelu_kernel(
    const float* __restrict__ h, const float* __restrict__ sP,
    const float* __restrict__ qP, const float* __restrict__ gamma,
    const float* __restrict__ beta, u16* __restrict__ h1b)
{
  __shared__ float sc[512], sh[512];
  int b = blockIdx.x, t = threadIdx.x;       // 256 blocks x 4 rows
  if (t < 128) {
    f32x4 S = {0, 0, 0, 0}, Q = {0, 0, 0, 0};
    #pragma unroll
    for (int p = 0; p < 32; ++p) {
      S += *(const f32x4*)(sP + p * 512 + t * 4);
      Q += *(const f32x4*)(qP + p * 512 + t * 4);
    }
    f32x4 g = *(const f32x4*)(gamma + t * 4);
    f32x4 be = *(const f32x4*)(beta + t * 4);
    #pragma unroll
    for (int i = 0; i < 4; ++i) {
      float mean = S[i] * (1.0f / 1024.0f);
      float var  = Q[i] * (1.0f / 1024.0f) - mean * mean;  // biased, matches ref
      float s = g[i] * rsqrtf(var + 1e-5f);
      sc[t * 4 + i] = s; sh[t * 4 + i] = be[i] - mean * s;
    }
  }
  __syncthreads();
  int row = b * 4 + (t >> 6), c0 = (t & 63) * 8;
  f32x4 v0 = *(const f32x4*)(h + (size_t)row * 512 + c0);
  f32x4 v1 = *(const f32x4*)(h + (size_t)row * 512 + c0 + 4);
  u16x8 o;
  #pragma unroll
  for (int i = 0; i < 4; ++i) {
    float hn = v0[i] * sc[c0 + i] + sh[c0 + i];
    o[i] = f2bf(hn > 0.0f ? hn : expm1f(hn));              // ELU(alpha=1)
  }
  #pragma unroll
  for (int i = 0; i < 4; ++i) {
    float hn = v1[i] * sc[c0 + 4 + i] + sh[c0 + 4 + i];
    o[4 + i] = f2bf(hn > 0.0f ? hn : expm1f(hn));
  }
  *(u16x8*)(h1b + (size_t)row * 512 + c0) = o;
}

extern "C" void kernel_launch(void* const* d_in, const int* in_sizes, int n_in,
                              void* d_out, int out_size, void* d_ws, size_t ws_size,
                              hipStream_t stream)
{
  const float* x     = (const float*)d_in[0];
  const float* coef  = (const float*)d_in[1];
  const float* w1    = (const float*)d_in[2];
  const float* b1    = (const float*)d_in[3];
  const float* w2    = (const float*)d_in[4];
  const float* b2    = (const float*)d_in[5];
  const float* gamma = (const float*)d_in[6];
  const float* beta  = (const float*)d_in[7];
  float* out = (float*)d_out;

  char* ws = (char*)d_ws;
  u16* w1t  = (u16*)(ws);                          //  4 MB [4096][512] bf16
  u16* w2t  = (u16*)(ws + (4u << 20));             //  4 MB
  u16* xb   = (u16*)(ws + (8u << 20));             //  1 MB [1024][512] bf16
  float* h  = (float*)(ws + (9u << 20));           //  2 MB [1024][512] f32
  u16* h1b  = (u16*)(ws + (11u << 20));            //  1 MB [1024][512] bf16
  float* sP = (float*)(ws + (12u << 20));          // 64 KB [32][512] col sums
  float* qP = (float*)(ws + (12u << 20) + 131072); // 64 KB [32][512] col sumsq

  prep_kernel<<<1152, 256, 0, stream>>>(x, w1, w2, xb, w1t, w2t);
  gemm_direct<1><<<256, 512, 0, stream>>>(xb, w1t, coef, b1, h, sP, qP);
  bnelu_kernel<<<256, 256, 0, stream>>>(h, sP, qP, gamma, beta, h1b);
  gemm_direct<2><<<256, 512, 0, stream>>>(h1b, w2t, coef, b2, out, nullptr, nullptr);
}

// Round 7
// 44.978 us; speedup vs baseline: 6.9840x; 1.4867x over previous
//
#include <hip/hip_runtime.h>

// ExpertMLP R7: R6's 4-node LDS-free structure, but A/W stored in MFMA
// FRAGMENT ORDER so every fragment load is one coalesced 1KB wave-load
// (R6's direct loads were 16-cache-line scattered per instruction -> L1-bound).
// Packed layout: chunk(g,s,c,ri) at ((g*16+s)*64 + c*16 + ri)*8 elems, where
// row = g*16+ri (g=row>>4), k = s*32 + c*8 + j. Wave fragment (g,s) = lane l
// reads 16B at base(g,s) + l*16B.
//  prep:  x -> xbp (packed bf16); w1,w2 -> w1p,w2p (packed bf16, transposed)
//  gemm1: 256 blocks, 8 waves = 8 experts, 32x64 tile; coef-scale, tree blend,
//         bias, h (std layout) + col stat partials
//  bnelu: reduce partials -> BN params; elu(BN(h)) -> h1p (packed bf16)
//  gemm2: same as gemm1 on h1p -> out

typedef short bf16x8 __attribute__((ext_vector_type(8)));
typedef float f32x4 __attribute__((ext_vector_type(4)));
typedef unsigned short u16;
typedef u16 u16x8 __attribute__((ext_vector_type(8)));

__device__ __forceinline__ u16 f2bf(float f) {
  union { float f; unsigned u; } v; v.f = f;
  return (u16)((v.u + 0x7FFFu + ((v.u >> 16) & 1u)) >> 16);  // RNE
}

// ---------------- prep: pack x and W into fragment order --------------------
__global__ __launch_bounds__(256) void prep_kernel(
    const float* __restrict__ x, const float* __restrict__ w1,
    const float* __restrict__ w2, u16* __restrict__ xbp,
    u16* __restrict__ w1p, u16* __restrict__ w2p)
{
  int bid = blockIdx.x, t = threadIdx.x;
  __shared__ float ld[64][65];               // +1 pad breaks col-read conflicts
  if (bid < 64) {                            // pack x (row-panel g = bid)
    int g = bid, ri = t & 15, q = t >> 4;
    #pragma unroll
    for (int rep = 0; rep < 4; ++rep) {
      int chunk = rep * 16 + q;              // 0..63 = (s,c)
      int s = chunk >> 2, c = chunk & 3;
      const float* src = x + (size_t)(g * 16 + ri) * 512 + s * 32 + c * 8;
      f32x4 v0 = *(const f32x4*)src;
      f32x4 v1 = *(const f32x4*)(src + 4);
      u16x8 o;
      #pragma unroll
      for (int i = 0; i < 4; ++i) { o[i] = f2bf(v0[i]); o[4 + i] = f2bf(v1[i]); }
      *(u16x8*)(xbp + ((size_t)(g * 16 + s) * 64 + c * 16 + ri) * 8) = o;
    }
    return;
  }
  int job = bid - 64;                        // 1024 jobs: 2 weights * 8 e * 64 tiles
  const float* src = (job >> 9) ? w2 : w1;
  u16* dst = (job >> 9) ? w2p : w1p;
  int rem = job & 511, e = rem >> 6, tl = rem & 63;
  int kt = tl >> 3, nt = tl & 7;             // source 64x64 tile at (kt,nt)
  #pragma unroll
  for (int j = 0; j < 4; ++j) {              // read [k][n] coalesced
    int kr = j * 16 + (t >> 4), nc = (t & 15) * 4;
    f32x4 v = *(const f32x4*)(src + (size_t)(e * 512 + kt * 64 + kr) * 512 + nt * 64 + nc);
    ld[kr][nc] = v.x; ld[kr][nc + 1] = v.y; ld[kr][nc + 2] = v.z; ld[kr][nc + 3] = v.w;
  }
  __syncthreads();
  #pragma unroll
  for (int rep = 0; rep < 2; ++rep) {        // write packed: 1KB contiguous / 64 lanes
    int gidx = rep * 256 + t;                // 0..511
    int ri = gidx & 15, c = (gidx >> 4) & 3, sl = (gidx >> 6) & 1, grp = gidx >> 7;
    int n_local = grp * 16 + ri;
    int gn = nt * 4 + grp;                   // B row-group (n>>4)
    int s = kt * 2 + sl;                     // global k-step
    int k0 = sl * 32 + c * 8;
    u16x8 o;
    #pragma unroll
    for (int i = 0; i < 8; ++i) o[i] = f2bf(ld[k0 + i][n_local]);
    *(u16x8*)(dst + ((size_t)((e * 32 + gn) * 16 + s) * 64 + c * 16 + ri) * 8) = o;
  }
}

// ---------------- packed-fragment blended GEMM ------------------------------
// 256 blocks (nt = bid&7 -> one XCD keeps its 512KB B panel L2-hot), 8 waves =
// 8 experts, 32x64 tile/block, K=512/wave. All fragment loads coalesced.
template <int LAYER>
__global__ __launch_bounds__(512, 2) void gemm_packed(
    const u16* __restrict__ Ap,       // packed [64g][16s][64][8]
    const u16* __restrict__ Wp,       // packed [8e*32gn][16s][64][8]
    const float* __restrict__ coef,   // [1024][8]
    const float* __restrict__ bias,   // [8][512]
    float* __restrict__ Out,          // h (f32, std layout) or out
    float* __restrict__ sP, float* __restrict__ qP)   // [32][512] partials
{
  int raw = blockIdx.x;
  int nt = raw & 7, mt = raw >> 3;
  int t = threadIdx.x, l = t & 63, e = t >> 6;
  __shared__ float red[4][32 * 68];          // 4 reduce slots, padded rows

  const u16* Ab = Ap + (size_t)(mt * 2) * 16 * 512 + l * 8;          // g=mt*2+m
  const u16* Bb = Wp + (size_t)(e * 32 + nt * 4) * 16 * 512 + l * 8; // gn=nt*4+n

  f32x4 acc[2][4] = {};
  bf16x8 bfr[2][4];
  #pragma unroll
  for (int n = 0; n < 4; ++n)                // preload B step 0
    bfr[0][n] = *(const bf16x8*)(Bb + (size_t)n * 16 * 512);

  #pragma unroll
  for (int s = 0; s < 16; ++s) {             // fully unrolled: static dbuf idx
    const int cur = s & 1, nxt = cur ^ 1;
    if (s < 15) {
      #pragma unroll
      for (int n = 0; n < 4; ++n)            // prefetch next B (coalesced, L2)
        bfr[nxt][n] = *(const bf16x8*)(Bb + (size_t)n * 16 * 512 + (s + 1) * 512);
    }
    bf16x8 af[2];
    #pragma unroll
    for (int m = 0; m < 2; ++m)              // A fragment (coalesced, L1-hot)
      af[m] = *(const bf16x8*)(Ab + (size_t)m * 16 * 512 + s * 512);
    #pragma unroll
    for (int m = 0; m < 2; ++m)
      #pragma unroll
      for (int n = 0; n < 4; ++n)
        acc[m][n] = __builtin_amdgcn_mfma_f32_16x16x32_bf16(af[m], bfr[cur][n], acc[m][n], 0, 0, 0);
  }

  // scale by coef[row, e] (C/D layout: row=(l>>4)*4+r+16m, col=n*16+(l&15))
  int rl = (l >> 4) * 4;
  #pragma unroll
  for (int m = 0; m < 2; ++m) {
    #pragma unroll
    for (int r = 0; r < 4; ++r) {
      float cf = coef[(size_t)(mt * 32 + m * 16 + rl + r) * 8 + e];
      #pragma unroll
      for (int n = 0; n < 4; ++n) acc[m][n][r] *= cf;
    }
  }

  // fixed-order tree reduce across the 8 expert-waves (deterministic)
#define RED_STORE(slot)                                                       \
  { _Pragma("unroll") for (int m = 0; m < 2; ++m)                             \
    _Pragma("unroll") for (int n = 0; n < 4; ++n)                             \
    _Pragma("unroll") for (int r = 0; r < 4; ++r)                             \
      red[slot][(m * 16 + rl + r) * 68 + n * 16 + (l & 15)] = acc[m][n][r]; }
#define RED_ADD(slot)                                                         \
  { _Pragma("unroll") for (int m = 0; m < 2; ++m)                             \
    _Pragma("unroll") for (int n = 0; n < 4; ++n)                             \
    _Pragma("unroll") for (int r = 0; r < 4; ++r)                             \
      acc[m][n][r] += red[slot][(m * 16 + rl + r) * 68 + n * 16 + (l & 15)]; }

  if (e >= 4) RED_STORE(e - 4);
  __syncthreads();
  if (e < 4) RED_ADD(e);
  __syncthreads();
  if (e == 2 || e == 3) RED_STORE(e - 2);
  __syncthreads();
  if (e < 2) RED_ADD(e);
  __syncthreads();
  if (e == 1) RED_STORE(0);
  __syncthreads();

  if (e == 0) {                              // wave 0: bias blend + write + stats
    RED_ADD(0);
    int col0 = nt * 64;
    float bcol[4][8];                        // bias[e2][col(n)] hoisted
    #pragma unroll
    for (int n = 0; n < 4; ++n)
      #pragma unroll
      for (int e2 = 0; e2 < 8; ++e2)
        bcol[n][e2] = bias[e2 * 512 + col0 + n * 16 + (l & 15)];
    float sS[4] = {0.f, 0.f, 0.f, 0.f}, sQ[4] = {0.f, 0.f, 0.f, 0.f};
    #pragma unroll
    for (int m = 0; m < 2; ++m)
      #pragma unroll
      for (int r = 0; r < 4; ++r) {
        int rowg = mt * 32 + m * 16 + rl + r;
        f32x4 c0 = *(const f32x4*)(coef + (size_t)rowg * 8);
        f32x4 c1 = *(const f32x4*)(coef + (size_t)rowg * 8 + 4);
        #pragma unroll
        for (int n = 0; n < 4; ++n) {
          float bb = c0[0]*bcol[n][0] + c0[1]*bcol[n][1] + c0[2]*bcol[n][2] + c0[3]*bcol[n][3]
                   + c1[0]*bcol[n][4] + c1[1]*bcol[n][5] + c1[2]*bcol[n][6] + c1[3]*bcol[n][7];
          float v = acc[m][n][r] + bb;
          Out[(size_t)rowg * 512 + col0 + n * 16 + (l & 15)] = v;
          if constexpr (LAYER == 1) { sS[n] += v; sQ[n] += v * v; }
        }
      }
    if constexpr (LAYER == 1) {              // col sums over 32 rows -> slot [mt]
      #pragma unroll
      for (int n = 0; n < 4; ++n) {
        sS[n] += __shfl_xor(sS[n], 16); sS[n] += __shfl_xor(sS[n], 32);
        sQ[n] += __shfl_xor(sQ[n], 16); sQ[n] += __shfl_xor(sQ[n], 32);
      }
      if (l < 16) {
        #pragma unroll
        for (int n = 0; n < 4; ++n) {
          sP[mt * 512 + col0 + n * 16 + l] = sS[n];
          qP[mt * 512 + col0 + n * 16 + l] = sQ[n];
        }
      }
    }
  }
#undef RED_STORE
#undef RED_ADD
}

// ---------------- bnelu: reduce partials; elu(BN(h)) -> packed bf16 ---------
__global__ __launch_bounds__(256) void bnelu_kernel(
    const float* __restrict__ h, const float* __restrict__ sP,
    const float* __restrict__ qP, const float* __restrict__ gamma,
    const float* __restrict__ beta, u16* __restrict__ h1p)
{
  __shared__ float sc[512], sh[512];
  int g = blockIdx.x, t = threadIdx.x;       // 64 blocks = row-panels
  if (t < 128) {
    f32x4 S = {0, 0, 0, 0}, Q = {0, 0, 0, 0};
    #pragma unroll
    for (int p = 0; p < 32; ++p) {
      S += *(const f32x4*)(sP + p * 512 + t * 4);
      Q += *(const f32x4*)(qP + p * 512 + t * 4);
    }
    f32x4 gm = *(const f32x4*)(gamma + t * 4);
    f32x4 be = *(const f32x4*)(beta + t * 4);
    #pragma unroll
    for (int i = 0; i < 4; ++i) {
      float mean = S[i] * (1.0f / 1024.0f);
      float var  = Q[i] * (1.0f / 1024.0f) - mean * mean;  // biased, matches ref
      float s = gm[i] * rsqrtf(var + 1e-5f);
      sc[t * 4 + i] = s; sh[t * 4 + i] = be[i] - mean * s;
    }
  }
  __syncthreads();
  int ri = t & 15, q = t >> 4;
  #pragma unroll
  for (int rep = 0; rep < 4; ++rep) {
    int chunk = rep * 16 + q;                // (s,c)
    int s = chunk >> 2, c = chunk & 3;
    int row = g * 16 + ri, col0 = s * 32 + c * 8;
    f32x4 v0 = *(const f32x4*)(h + (size_t)row * 512 + col0);
    f32x4 v1 = *(const f32x4*)(h + (size_t)row * 512 + col0 + 4);
    u16x8 o;
    #pragma unroll
    for (int i = 0; i < 4; ++i) {
      float hn = v0[i] * sc[col0 + i] + sh[col0 + i];
      o[i] = f2bf(hn > 0.0f ? hn : expm1f(hn));            // ELU(alpha=1)
    }
    #pragma unroll
    for (int i = 0; i < 4; ++i) {
      float hn = v1[i] * sc[col0 + 4 + i] + sh[col0 + 4 + i];
      o[4 + i] = f2bf(hn > 0.0f ? hn : expm1f(hn));
    }
    *(u16x8*)(h1p + ((size_t)(g * 16 + s) * 64 + c * 16 + ri) * 8) = o;
  }
}

extern "C" void kernel_launch(void* const* d_in, const int* in_sizes, int n_in,
                              void* d_out, int out_size, void* d_ws, size_t ws_size,
                              hipStream_t stream)
{
  const float* x     = (const float*)d_in[0];
  const float* coef  = (const float*)d_in[1];
  const float* w1    = (const float*)d_in[2];
  const float* b1    = (const float*)d_in[3];
  const float* w2    = (const float*)d_in[4];
  const float* b2    = (const float*)d_in[5];
  const float* gamma = (const float*)d_in[6];
  const float* beta  = (const float*)d_in[7];
  float* out = (float*)d_out;

  char* ws = (char*)d_ws;
  u16* w1p  = (u16*)(ws);                          //  4 MB packed bf16
  u16* w2p  = (u16*)(ws + (4u << 20));             //  4 MB
  u16* xbp  = (u16*)(ws + (8u << 20));             //  1 MB packed bf16
  float* h  = (float*)(ws + (9u << 20));           //  2 MB [1024][512] f32
  u16* h1p  = (u16*)(ws + (11u << 20));            //  1 MB packed bf16
  float* sP = (float*)(ws + (12u << 20));          // 64 KB [32][512] col sums
  float* qP = (float*)(ws + (12u << 20) + 131072); // 64 KB [32][512] col sumsq

  prep_kernel<<<1088, 256, 0, stream>>>(x, w1, w2, xbp, w1p, w2p);
  gemm_packed<1><<<256, 512, 0, stream>>>(xbp, w1p, coef, b1, h, sP, qP);
  bnelu_kernel<<<64, 256, 0, stream>>>(h, sP, qP, gamma, beta, h1p);
  gemm_packed<2><<<256, 512, 0, stream>>>(h1p, w2p, coef, b2, out, nullptr, nullptr);
}

// Round 8
// 39.992 us; speedup vs baseline: 7.8549x; 1.1247x over previous
//
#include <hip/hip_runtime.h>

// ExpertMLP R8: 3 nodes.
//  n1 prep1:  x -> xbp (packed bf16); w1 -> w1p (packed bf16)
//  n2 gemm1 (+w2 prep): bid<256: P-blend gemm, epilogue writes hb PACKED bf16
//     + col stat partials. bid>=256: w2 -> w2p transpose (needed only in n3).
//  n3 gemm2: stats -> BN params; hb -> BN+ELU -> As (LDS, shared by 8 waves);
//     MFMA; blend epilogue -> out.
// Packed layout: chunk(g,s,c,ri) at ((g*16+s)*64 + c*16 + ri)*8 elems;
// row = g*16+ri, k = s*32+c*8+j. Fragment (g,s) load = base + lane*16B.

typedef short bf16x8 __attribute__((ext_vector_type(8)));
typedef float f32x4 __attribute__((ext_vector_type(4)));
typedef unsigned short u16;
typedef u16 u16x8 __attribute__((ext_vector_type(8)));

__device__ __forceinline__ u16 f2bf(float f) {
  union { float f; unsigned u; } v; v.f = f;
  return (u16)((v.u + 0x7FFFu + ((v.u >> 16) & 1u)) >> 16);  // RNE
}
__device__ __forceinline__ float bf2f(u16 u) {
  union { unsigned u; float f; } v; v.u = (unsigned)u << 16; return v.f;
}

// ---------------- n1: x pack + w1 transpose-pack ----------------------------
__global__ __launch_bounds__(256) void prep1_kernel(
    const float* __restrict__ x, const float* __restrict__ w1,
    u16* __restrict__ xbp, u16* __restrict__ w1p)
{
  int bid = blockIdx.x, t = threadIdx.x;
  __shared__ float ld[64][65];
  if (bid < 64) {                            // pack x (row-panel g = bid)
    int g = bid, ri = t & 15, q = t >> 4;
    #pragma unroll
    for (int rep = 0; rep < 4; ++rep) {
      int chunk = rep * 16 + q;              // (s,c)
      int s = chunk >> 2, c = chunk & 3;
      const float* src = x + (size_t)(g * 16 + ri) * 512 + s * 32 + c * 8;
      f32x4 v0 = *(const f32x4*)src;
      f32x4 v1 = *(const f32x4*)(src + 4);
      u16x8 o;
      #pragma unroll
      for (int i = 0; i < 4; ++i) { o[i] = f2bf(v0[i]); o[4 + i] = f2bf(v1[i]); }
      *(u16x8*)(xbp + ((size_t)(g * 16 + s) * 64 + c * 16 + ri) * 8) = o;
    }
    return;
  }
  int job = bid - 64;                        // 512 w1 tiles
  int e = job >> 6, tl = job & 63;
  int kt = tl >> 3, nt = tl & 7;
  #pragma unroll
  for (int j = 0; j < 4; ++j) {              // read [k][n] coalesced
    int kr = j * 16 + (t >> 4), nc = (t & 15) * 4;
    f32x4 v = *(const f32x4*)(w1 + (size_t)(e * 512 + kt * 64 + kr) * 512 + nt * 64 + nc);
    ld[kr][nc] = v.x; ld[kr][nc + 1] = v.y; ld[kr][nc + 2] = v.z; ld[kr][nc + 3] = v.w;
  }
  __syncthreads();
  #pragma unroll
  for (int rep = 0; rep < 2; ++rep) {        // packed write, coalesced
    int gidx = rep * 256 + t;
    int ri = gidx & 15, c = (gidx >> 4) & 3, sl = (gidx >> 6) & 1, grp = gidx >> 7;
    int n_local = grp * 16 + ri;
    int gn = nt * 4 + grp, s = kt * 2 + sl, k0 = sl * 32 + c * 8;
    u16x8 o;
    #pragma unroll
    for (int i = 0; i < 8; ++i) o[i] = f2bf(ld[k0 + i][n_local]);
    *(u16x8*)(w1p + ((size_t)((e * 32 + gn) * 16 + s) * 64 + c * 16 + ri) * 8) = o;
  }
}

// ---------------- n2: gemm1 (bid<256) + w2 transpose (bid>=256) -------------
__global__ __launch_bounds__(512, 2) void gemm1_prep2(
    const u16* __restrict__ Ap, const u16* __restrict__ Wp,
    const float* __restrict__ coef, const float* __restrict__ bias,
    const float* __restrict__ w2, u16* __restrict__ w2p,
    u16* __restrict__ hb, float* __restrict__ sP, float* __restrict__ qP)
{
  __shared__ __align__(16) char smem[38912];
  int t = threadIdx.x;
  if (blockIdx.x >= 256) {                   // ---- w2 transpose-pack, 512 thr
    float (*ld)[65] = (float (*)[65])smem;   // 16.6 KB of smem
    int job = blockIdx.x - 256;
    int e = job >> 6, tl = job & 63;
    int kt = tl >> 3, nt = tl & 7;
    #pragma unroll
    for (int j = 0; j < 2; ++j) {
      int kr = j * 32 + (t >> 4), nc = (t & 15) * 4;
      f32x4 v = *(const f32x4*)(w2 + (size_t)(e * 512 + kt * 64 + kr) * 512 + nt * 64 + nc);
      ld[kr][nc] = v.x; ld[kr][nc + 1] = v.y; ld[kr][nc + 2] = v.z; ld[kr][nc + 3] = v.w;
    }
    __syncthreads();
    {
      int ri = t & 15, c = (t >> 4) & 3, sl = (t >> 6) & 1, grp = t >> 7;
      int n_local = grp * 16 + ri;
      int gn = nt * 4 + grp, s = kt * 2 + sl, k0 = sl * 32 + c * 8;
      u16x8 o;
      #pragma unroll
      for (int i = 0; i < 8; ++i) o[i] = f2bf(ld[k0 + i][n_local]);
      *(u16x8*)(w2p + ((size_t)((e * 32 + gn) * 16 + s) * 64 + c * 16 + ri) * 8) = o;
    }
    return;
  }
  // ---- gemm1: 32x64 tile, 8 waves = 8 experts, K=512 ----
  float* red = (float*)smem;                 // [4][32*68] = 34.8 KB
  int raw = blockIdx.x, nt = raw & 7, mt = raw >> 3;
  int l = t & 63, e = t >> 6;

  const u16* Ab = Ap + (size_t)(mt * 2) * 16 * 512 + l * 8;
  const u16* Bb = Wp + (size_t)(e * 32 + nt * 4) * 16 * 512 + l * 8;

  f32x4 acc[2][4] = {};
  bf16x8 bfr[2][4];
  #pragma unroll
  for (int n = 0; n < 4; ++n)
    bfr[0][n] = *(const bf16x8*)(Bb + (size_t)n * 16 * 512);

  #pragma unroll
  for (int s = 0; s < 16; ++s) {
    const int cur = s & 1, nxt = cur ^ 1;
    if (s < 15) {
      #pragma unroll
      for (int n = 0; n < 4; ++n)
        bfr[nxt][n] = *(const bf16x8*)(Bb + (size_t)n * 16 * 512 + (s + 1) * 512);
    }
    bf16x8 af[2];
    #pragma unroll
    for (int m = 0; m < 2; ++m)
      af[m] = *(const bf16x8*)(Ab + (size_t)m * 16 * 512 + s * 512);
    #pragma unroll
    for (int m = 0; m < 2; ++m)
      #pragma unroll
      for (int n = 0; n < 4; ++n)
        acc[m][n] = __builtin_amdgcn_mfma_f32_16x16x32_bf16(af[m], bfr[cur][n], acc[m][n], 0, 0, 0);
  }

  int rl = (l >> 4) * 4;
  #pragma unroll
  for (int m = 0; m < 2; ++m)
    #pragma unroll
    for (int r = 0; r < 4; ++r) {
      float cf = coef[(size_t)(mt * 32 + m * 16 + rl + r) * 8 + e];
      #pragma unroll
      for (int n = 0; n < 4; ++n) acc[m][n][r] *= cf;
    }

#define RED_STORE(slot)                                                       \
  { _Pragma("unroll") for (int m = 0; m < 2; ++m)                             \
    _Pragma("unroll") for (int n = 0; n < 4; ++n)                             \
    _Pragma("unroll") for (int r = 0; r < 4; ++r)                             \
      red[(slot) * 2176 + (m * 16 + rl + r) * 68 + n * 16 + (l & 15)] = acc[m][n][r]; }
#define RED_ADD(slot)                                                         \
  { _Pragma("unroll") for (int m = 0; m < 2; ++m)                             \
    _Pragma("unroll") for (int n = 0; n < 4; ++n)                             \
    _Pragma("unroll") for (int r = 0; r < 4; ++r)                             \
      acc[m][n][r] += red[(slot) * 2176 + (m * 16 + rl + r) * 68 + n * 16 + (l & 15)]; }

  if (e >= 4) RED_STORE(e - 4);
  __syncthreads();
  if (e < 4) RED_ADD(e);
  __syncthreads();
  if (e == 2 || e == 3) RED_STORE(e - 2);
  __syncthreads();
  if (e < 2) RED_ADD(e);
  __syncthreads();
  if (e == 1) RED_STORE(0);
  __syncthreads();

  if (e == 0) {                              // wave 0: bias blend -> red0 + stats
    RED_ADD(0);
    int col0 = nt * 64;
    float bcol[4][8];
    #pragma unroll
    for (int n = 0; n < 4; ++n)
      #pragma unroll
      for (int e2 = 0; e2 < 8; ++e2)
        bcol[n][e2] = bias[e2 * 512 + col0 + n * 16 + (l & 15)];
    float sS[4] = {0.f, 0.f, 0.f, 0.f}, sQ[4] = {0.f, 0.f, 0.f, 0.f};
    #pragma unroll
    for (int m = 0; m < 2; ++m)
      #pragma unroll
      for (int r = 0; r < 4; ++r) {
        int rowg = mt * 32 + m * 16 + rl + r;
        f32x4 c0 = *(const f32x4*)(coef + (size_t)rowg * 8);
        f32x4 c1 = *(const f32x4*)(coef + (size_t)rowg * 8 + 4);
        #pragma unroll
        for (int n = 0; n < 4; ++n) {
          float bb = c0[0]*bcol[n][0] + c0[1]*bcol[n][1] + c0[2]*bcol[n][2] + c0[3]*bcol[n][3]
                   + c1[0]*bcol[n][4] + c1[1]*bcol[n][5] + c1[2]*bcol[n][6] + c1[3]*bcol[n][7];
          float v = acc[m][n][r] + bb;
          red[(m * 16 + rl + r) * 68 + n * 16 + (l & 15)] = v;   // blended tile
          if (true) { sS[n] += v; sQ[n] += v * v; }
        }
      }
    #pragma unroll
    for (int n = 0; n < 4; ++n) {            // col sums over 32 rows
      sS[n] += __shfl_xor(sS[n], 16); sS[n] += __shfl_xor(sS[n], 32);
      sQ[n] += __shfl_xor(sQ[n], 16); sQ[n] += __shfl_xor(sQ[n], 32);
    }
    if (l < 16) {
      #pragma unroll
      for (int n = 0; n < 4; ++n) {
        sP[mt * 512 + col0 + n * 16 + l] = sS[n];
        qP[mt * 512 + col0 + n * 16 + l] = sQ[n];
      }
    }
    asm volatile("s_waitcnt lgkmcnt(0)" ::: "memory");  // red0 writes drained
    __builtin_amdgcn_sched_barrier(0);
    int c = l >> 4, ri = l & 15;             // packed hb write: 1KB/issue
    #pragma unroll
    for (int g = 0; g < 2; ++g)
      #pragma unroll
      for (int sr = 0; sr < 2; ++sr) {
        f32x4 a = *(const f32x4*)&red[(g * 16 + ri) * 68 + sr * 32 + c * 8];
        f32x4 b = *(const f32x4*)&red[(g * 16 + ri) * 68 + sr * 32 + c * 8 + 4];
        u16x8 o;
        #pragma unroll
        for (int i = 0; i < 4; ++i) { o[i] = f2bf(a[i]); o[4 + i] = f2bf(b[i]); }
        *(u16x8*)(hb + ((size_t)((mt * 2 + g) * 16 + nt * 2 + sr) * 64 + c * 16 + ri) * 8) = o;
      }
  }
#undef RED_STORE
#undef RED_ADD
}

// ---------------- n3: gemm2 with fused BN+ELU A-staging ---------------------
__global__ __launch_bounds__(512, 2) void gemm2_kernel(
    const u16* __restrict__ hb, const u16* __restrict__ Wp,
    const float* __restrict__ coef, const float* __restrict__ bias,
    const float* __restrict__ gamma, const float* __restrict__ beta,
    const float* __restrict__ sP, const float* __restrict__ qP,
    float* __restrict__ Out)
{
  __shared__ __align__(16) char smem[38912]; // As (32KB) union red (34.8KB)
  __shared__ float sc[512], sh[512];
  u16* As = (u16*)smem;
  float* red = (float*)smem;
  int raw = blockIdx.x, nt = raw & 7, mt = raw >> 3;
  int t = threadIdx.x, l = t & 63, e = t >> 6;

  const u16* Bb = Wp + (size_t)(e * 32 + nt * 4) * 16 * 512 + l * 8;
  bf16x8 bfr[2][4];
  #pragma unroll
  for (int n = 0; n < 4; ++n)                // issue B preload early
    bfr[0][n] = *(const bf16x8*)(Bb + (size_t)n * 16 * 512);

  {                                          // BN params: one col per thread
    float S = 0.f, Q = 0.f;
    #pragma unroll
    for (int p = 0; p < 32; ++p) { S += sP[p * 512 + t]; Q += qP[p * 512 + t]; }
    float mean = S * (1.0f / 1024.0f);
    float var  = Q * (1.0f / 1024.0f) - mean * mean;     // biased, matches ref
    float s_ = gamma[t] * rsqrtf(var + 1e-5f);
    sc[t] = s_; sh[t] = beta[t] - mean * s_;
  }
  __syncthreads();

  const u16* hsrc = hb + (size_t)mt * 16384; // this block's 32x512 slab (packed)
  #pragma unroll
  for (int rep = 0; rep < 4; ++rep) {        // BN+ELU transform -> As (linear)
    int ci = rep * 512 + t;                  // slab chunk id
    u16x8 hv = *(const u16x8*)(hsrc + (size_t)ci * 8);
    int s = (ci >> 6) & 15, c = (l >> 4) & 3;
    int k0 = s * 32 + c * 8;
    f32x4 s0 = *(const f32x4*)&sc[k0], s1 = *(const f32x4*)&sc[k0 + 4];
    f32x4 h0 = *(const f32x4*)&sh[k0], h1 = *(const f32x4*)&sh[k0 + 4];
    u16x8 o;
    #pragma unroll
    for (int i = 0; i < 4; ++i) {
      float v = bf2f(hv[i]) * s0[i] + h0[i];
      o[i] = f2bf(v > 0.f ? v : expm1f(v));
    }
    #pragma unroll
    for (int i = 0; i < 4; ++i) {
      float v = bf2f(hv[4 + i]) * s1[i] + h1[i];
      o[4 + i] = f2bf(v > 0.f ? v : expm1f(v));
    }
    *(u16x8*)&As[(size_t)ci * 8] = o;
  }
  __syncthreads();

  f32x4 acc[2][4] = {};
  #pragma unroll
  for (int s = 0; s < 16; ++s) {
    const int cur = s & 1, nxt = cur ^ 1;
    if (s < 15) {
      #pragma unroll
      for (int n = 0; n < 4; ++n)
        bfr[nxt][n] = *(const bf16x8*)(Bb + (size_t)n * 16 * 512 + (s + 1) * 512);
    }
    bf16x8 af[2];
    #pragma unroll
    for (int m = 0; m < 2; ++m)              // A from LDS, lane-linear: no conflicts
      af[m] = *(const bf16x8*)&As[((m * 16 + s) * 64 + l) * 8];
    #pragma unroll
    for (int m = 0; m < 2; ++m)
      #pragma unroll
      for (int n = 0; n < 4; ++n)
        acc[m][n] = __builtin_amdgcn_mfma_f32_16x16x32_bf16(af[m], bfr[cur][n], acc[m][n], 0, 0, 0);
  }
  __syncthreads();                           // As -> red reuse barrier

  int rl = (l >> 4) * 4;
  #pragma unroll
  for (int m = 0; m < 2; ++m)
    #pragma unroll
    for (int r = 0; r < 4; ++r) {
      float cf = coef[(size_t)(mt * 32 + m * 16 + rl + r) * 8 + e];
      #pragma unroll
      for (int n = 0; n < 4; ++n) acc[m][n][r] *= cf;
    }

#define RED_STORE(slot)                                                       \
  { _Pragma("unroll") for (int m = 0; m < 2; ++m)                             \
    _Pragma("unroll") for (int n = 0; n < 4; ++n)                             \
    _Pragma("unroll") for (int r = 0; r < 4; ++r)                             \
      red[(slot) * 2176 + (m * 16 + rl + r) * 68 + n * 16 + (l & 15)] = acc[m][n][r]; }
#define RED_ADD(slot)                                                         \
  { _Pragma("unroll") for (int m = 0; m < 2; ++m)                             \
    _Pragma("unroll") for (int n = 0; n < 4; ++n)                             \
    _Pragma("unroll") for (int r = 0; r < 4; ++r)                             \
      acc[m][n][r] += red[(slot) * 2176 + (m * 16 + rl + r) * 68 + n * 16 + (l & 15)]; }

  if (e >= 4) RED_STORE(e - 4);
  __syncthreads();
  if (e < 4) RED_ADD(e);
  __syncthreads();
  if (e == 2 || e == 3) RED_STORE(e - 2);
  __syncthreads();
  if (e < 2) RED_ADD(e);
  __syncthreads();
  if (e == 1) RED_STORE(0);
  __syncthreads();

  if (e == 0) {                              // bias blend + std-layout out
    RED_ADD(0);
    int col0 = nt * 64;
    float bcol[4][8];
    #pragma unroll
    for (int n = 0; n < 4; ++n)
      #pragma unroll
      for (int e2 = 0; e2 < 8; ++e2)
        bcol[n][e2] = bias[e2 * 512 + col0 + n * 16 + (l & 15)];
    #pragma unroll
    for (int m = 0; m < 2; ++m)
      #pragma unroll
      for (int r = 0; r < 4; ++r) {
        int rowg = mt * 32 + m * 16 + rl + r;
        f32x4 c0 = *(const f32x4*)(coef + (size_t)rowg * 8);
        f32x4 c1 = *(const f32x4*)(coef + (size_t)rowg * 8 + 4);
        #pragma unroll
        for (int n = 0; n < 4; ++n) {
          float bb = c0[0]*bcol[n][0] + c0[1]*bcol[n][1] + c0[2]*bcol[n][2] + c0[3]*bcol[n][3]
                   + c1[0]*bcol[n][4] + c1[1]*bcol[n][5] + c1[2]*bcol[n][6] + c1[3]*bcol[n][7];
          Out[(size_t)rowg * 512 + col0 + n * 16 + (l & 15)] = acc[m][n][r] + bb;
        }
      }
  }
#undef RED_STORE
#undef RED_ADD
}

extern "C" void kernel_launch(void* const* d_in, const int* in_sizes, int n_in,
                              void* d_out, int out_size, void* d_ws, size_t ws_size,
                              hipStream_t stream)
{
  const float* x     = (const float*)d_in[0];
  const float* coef  = (const float*)d_in[1];
  const float* w1    = (const float*)d_in[2];
  const float* b1    = (const float*)d_in[3];
  const float* w2    = (const float*)d_in[4];
  const float* b2    = (const float*)d_in[5];
  const float* gamma = (const float*)d_in[6];
  const float* beta  = (const float*)d_in[7];
  float* out = (float*)d_out;

  char* ws = (char*)d_ws;
  u16* w1p  = (u16*)(ws);                          //  4 MB packed bf16
  u16* w2p  = (u16*)(ws + (4u << 20));             //  4 MB
  u16* xbp  = (u16*)(ws + (8u << 20));             //  1 MB packed bf16
  u16* hb   = (u16*)(ws + (9u << 20));             //  1 MB packed bf16 (pre-BN h)
  float* sP = (float*)(ws + (10u << 20));          // 64 KB [32][512] col sums
  float* qP = (float*)(ws + (10u << 20) + 65536);  // 64 KB [32][512] col sumsq

  prep1_kernel<<<576, 256, 0, stream>>>(x, w1, xbp, w1p);
  gemm1_prep2<<<768, 512, 0, stream>>>(xbp, w1p, coef, b1, w2, w2p, hb, sP, qP);
  gemm2_kernel<<<256, 512, 0, stream>>>(hb, w2p, coef, b2, gamma, beta, sP, qP, out);
}